// Round 1
// baseline (6677.208 us; speedup 1.0000x reference)
//
#include <hip/hip_runtime.h>

// FiLM-GRU, T=128, B=1024, IN=128, H=256, L=2, all fp32 in/out.
// Strategy: batch-partitioned persistent blocks (64 blocks x 512 threads,
// 16 batch rows each), f16 MFMA (16x16x32) for all projections, h carried in
// fp32 registers, weights pre-packed to MFMA B-fragment layout in d_ws.

typedef __attribute__((ext_vector_type(8))) _Float16 half8;
typedef __attribute__((ext_vector_type(4))) float   f32x4;

#define T_  128
#define B_  1024
#define IN_ 128
#define H_  256

// packed weight layout in d_ws (f16): chunks of 512 = one 16(N)x32(K) B-frag,
// element [lane*8 + j] = W[ntile*16 + (lane&15)][ktile*32 + (lane>>4)*8 + j]
#define WX0_OFF 0
#define WX0_N   (48 * 4 * 512)
#define WH0_OFF (WX0_OFF + WX0_N)
#define WH0_N   (48 * 8 * 512)
#define WX1_OFF (WH0_OFF + WH0_N)
#define WX1_N   (48 * 8 * 512)
#define WH1_OFF (WX1_OFF + WX1_N)
#define WH1_N   (48 * 8 * 512)
#define WTOT    (WH1_OFF + WH1_N)   // 688128 f16 elements = 1.31 MB

__global__ void pack_weights_k(const float* __restrict__ Wx0, const float* __restrict__ Wh0,
                               const float* __restrict__ Wx1, const float* __restrict__ Wh1,
                               _Float16* __restrict__ wp)
{
    int p = blockIdx.x * blockDim.x + threadIdx.x;
    if (p >= WTOT) return;
    const float* src; int q, nk, K;
    if (p < WX1_OFF) {
        if (p < WH0_OFF) { src = Wx0; q = p - WX0_OFF; nk = 4; K = 128; }
        else             { src = Wh0; q = p - WH0_OFF; nk = 8; K = 256; }
    } else {
        if (p < WH1_OFF) { src = Wx1; q = p - WX1_OFF; nk = 8; K = 256; }
        else             { src = Wh1; q = p - WH1_OFF; nk = 8; K = 256; }
    }
    int chunk = q >> 9;          // nt*nk + kt
    int e     = q & 511;
    int nt = chunk / nk, kt = chunk - nt * nk;
    int lane = e >> 3, j = e & 7;
    int n = nt * 16 + (lane & 15);
    int k = kt * 32 + ((lane >> 4) << 3) + j;
    wp[p] = (_Float16)src[n * K + k];
}

__device__ __forceinline__ float sigmoid_(float v) { return 1.f / (1.f + __expf(-v)); }
__device__ __forceinline__ float tanh_(float v) {
    float e = __expf(2.f * v);
    return 1.f - 2.f / (e + 1.f);     // safe at +-inf
}

__device__ __forceinline__ half8 cvt_h8(const float* p) {
    f32x4 a = *(const f32x4*)p;
    f32x4 b = *(const f32x4*)(p + 4);
    half8 r;
    r[0] = (_Float16)a[0]; r[1] = (_Float16)a[1]; r[2] = (_Float16)a[2]; r[3] = (_Float16)a[3];
    r[4] = (_Float16)b[0]; r[5] = (_Float16)b[1]; r[6] = (_Float16)b[2]; r[7] = (_Float16)b[3];
    return r;
}

#define MFMA(a, b, c) __builtin_amdgcn_mfma_f32_16x16x32_f16((a), (b), (c), 0, 0, 0)

// A-fragment LDS layout (K up to 256 => 8 k-tiles of 32): chunk kt holds
// element [lane*8+j] = A[lane&15][kt*32 + (lane>>4)*8 + j]  (16 rows)
__launch_bounds__(512, 2)
__global__ void film_gru_k(const float* __restrict__ x,
                           const float* __restrict__ h_init,
                           const float* __restrict__ gammas,
                           const float* __restrict__ betas,
                           const float* __restrict__ bx0, const float* __restrict__ bh0,
                           const float* __restrict__ bx1, const float* __restrict__ bh1,
                           const _Float16* __restrict__ wp,
                           float* __restrict__ out)
{
    __shared__ __align__(16) _Float16 h0frag[8 * 512];   // 8 KB: layer0 h / layer1 x input
    __shared__ __align__(16) _Float16 h1frag[8 * 512];   // 8 KB: layer1 h

    const int tid  = threadIdx.x;
    const int Wv   = tid >> 6;        // wave 0..7, owns h-cols [32*Wv, 32*Wv+32)
    const int lane = tid & 63;
    const int l15  = lane & 15;
    const int lq   = lane >> 4;       // 0..3
    const int b0   = blockIdx.x * 16; // 16 batch rows per block

    // wave's 6 global N-tiles: z pair, r pair, n pair (gate rows 0/256/512 +)
    const int nts[6] = {2*Wv, 2*Wv + 1, 16 + 2*Wv, 17 + 2*Wv, 32 + 2*Wv, 33 + 2*Wv};

    // fp32 hidden state, per-lane: index [c*4+g], c=col-tile(0..1), g=reg(0..3)
    // covers (row = lq*4+g, col = Wv*32 + c*16 + l15)
    float hr0[8], hr1[8];
    #pragma unroll
    for (int c = 0; c < 2; c++) {
        #pragma unroll
        for (int g = 0; g < 4; g++) {
            int col = Wv * 32 + c * 16 + l15;
            int row = lq * 4 + g;
            float v0 = h_init[(size_t)(b0 + row) * H_ + col];
            float v1 = h_init[(size_t)B_ * H_ + (size_t)(b0 + row) * H_ + col];
            hr0[c * 4 + g] = v0;
            hr1[c * 4 + g] = v1;
            int fa = (col >> 5) * 512 + ((((col >> 3) & 3) << 4) | row) * 8 + (col & 7);
            h0frag[fa] = (_Float16)v0;
            h1frag[fa] = (_Float16)v1;
        }
    }
    __syncthreads();

    const f32x4 zero4 = {0.f, 0.f, 0.f, 0.f};

    for (int t = 0; t < T_; t++) {
        // ============ layer 0 GEMM: aX = x_t @ Wx0^T, aH = h0 @ Wh0^T ============
        f32x4 aX[6], aH[6];
        #pragma unroll
        for (int i = 0; i < 6; i++) { aX[i] = zero4; aH[i] = zero4; }

        const float* xbase = x + (size_t)t * B_ * IN_ + (size_t)(b0 + l15) * IN_ + lq * 8;
        #pragma unroll
        for (int kt = 0; kt < 4; kt++) {
            half8 a = cvt_h8(xbase + kt * 32);
            #pragma unroll
            for (int i = 0; i < 6; i++) {
                half8 b = *(const half8*)(wp + WX0_OFF + (size_t)(nts[i] * 4 + kt) * 512 + lane * 8);
                aX[i] = MFMA(a, b, aX[i]);
            }
        }
        #pragma unroll
        for (int kt = 0; kt < 8; kt++) {
            half8 a = *(const half8*)&h0frag[kt * 512 + lane * 8];
            #pragma unroll
            for (int i = 0; i < 6; i++) {
                half8 b = *(const half8*)(wp + WH0_OFF + (size_t)(nts[i] * 8 + kt) * 512 + lane * 8);
                aH[i] = MFMA(a, b, aH[i]);
            }
        }
        __syncthreads();   // all waves done reading h0frag

        // ============ layer 0 elementwise + FiLM ============
        #pragma unroll
        for (int c = 0; c < 2; c++) {
            #pragma unroll
            for (int g = 0; g < 4; g++) {
                int col = Wv * 32 + c * 16 + l15;
                int row = lq * 4 + g;
                float pz = (aX[c    ][g] + bx0[col])       + (aH[c    ][g] + bh0[col]);
                float pr = (aX[2 + c][g] + bx0[256 + col]) + (aH[2 + c][g] + bh0[256 + col]);
                float xn = aX[4 + c][g] + bx0[512 + col];
                float hn = aH[4 + c][g] + bh0[512 + col];
                float zg = sigmoid_(pz);
                float rg = sigmoid_(pr);
                float ng = tanh_(xn + rg * hn);
                float h  = (1.f - zg) * ng + zg * hr0[c * 4 + g];
                size_t gi = (size_t)(b0 + row) * H_ + col;
                h = gammas[gi] * h + betas[gi];
                hr0[c * 4 + g] = h;
                int fa = Wv * 512 + ((((col >> 3) & 3) << 4) | row) * 8 + (col & 7);
                h0frag[fa] = (_Float16)h;
            }
        }
        __syncthreads();   // h0frag (= out0 = new h0) visible

        // ============ layer 1 GEMM: aX = out0 @ Wx1^T, aH = h1 @ Wh1^T ============
        #pragma unroll
        for (int i = 0; i < 6; i++) { aX[i] = zero4; aH[i] = zero4; }
        #pragma unroll
        for (int kt = 0; kt < 8; kt++) {
            half8 a0 = *(const half8*)&h0frag[kt * 512 + lane * 8];
            half8 a1 = *(const half8*)&h1frag[kt * 512 + lane * 8];
            #pragma unroll
            for (int i = 0; i < 6; i++) {
                half8 bx = *(const half8*)(wp + WX1_OFF + (size_t)(nts[i] * 8 + kt) * 512 + lane * 8);
                aX[i] = MFMA(a0, bx, aX[i]);
                half8 bh = *(const half8*)(wp + WH1_OFF + (size_t)(nts[i] * 8 + kt) * 512 + lane * 8);
                aH[i] = MFMA(a1, bh, aH[i]);
            }
        }
        __syncthreads();   // all waves done reading h1frag

        // ============ layer 1 elementwise + FiLM + output ============
        #pragma unroll
        for (int c = 0; c < 2; c++) {
            #pragma unroll
            for (int g = 0; g < 4; g++) {
                int col = Wv * 32 + c * 16 + l15;
                int row = lq * 4 + g;
                float pz = (aX[c    ][g] + bx1[col])       + (aH[c    ][g] + bh1[col]);
                float pr = (aX[2 + c][g] + bx1[256 + col]) + (aH[2 + c][g] + bh1[256 + col]);
                float xn = aX[4 + c][g] + bx1[512 + col];
                float hn = aH[4 + c][g] + bh1[512 + col];
                float zg = sigmoid_(pz);
                float rg = sigmoid_(pr);
                float ng = tanh_(xn + rg * hn);
                float h  = (1.f - zg) * ng + zg * hr1[c * 4 + g];
                size_t gi = (size_t)B_ * H_ + (size_t)(b0 + row) * H_ + col;
                h = gammas[gi] * h + betas[gi];
                hr1[c * 4 + g] = h;
                out[(size_t)t * B_ * H_ + (size_t)(b0 + row) * H_ + col] = h;
                int fa = Wv * 512 + ((((col >> 3) & 3) << 4) | row) * 8 + (col & 7);
                h1frag[fa] = (_Float16)h;
            }
        }
        __syncthreads();   // h1frag visible for next step
    }

    // final states: out[T*B*H + layer*B*H + b*H + col]
    #pragma unroll
    for (int c = 0; c < 2; c++) {
        #pragma unroll
        for (int g = 0; g < 4; g++) {
            int col = Wv * 32 + c * 16 + l15;
            int row = lq * 4 + g;
            size_t base = (size_t)T_ * B_ * H_ + (size_t)(b0 + row) * H_ + col;
            out[base] = hr0[c * 4 + g];
            out[base + (size_t)B_ * H_] = hr1[c * 4 + g];
        }
    }
}

extern "C" void kernel_launch(void* const* d_in, const int* in_sizes, int n_in,
                              void* d_out, int out_size, void* d_ws, size_t ws_size,
                              hipStream_t stream)
{
    const float* x    = (const float*)d_in[0];
    const float* hini = (const float*)d_in[1];
    const float* gam  = (const float*)d_in[2];
    const float* bet  = (const float*)d_in[3];
    const float* Wx0  = (const float*)d_in[4];
    const float* bx0  = (const float*)d_in[5];
    const float* Wh0  = (const float*)d_in[6];
    const float* bh0  = (const float*)d_in[7];
    const float* Wx1  = (const float*)d_in[8];
    const float* bx1  = (const float*)d_in[9];
    const float* Wh1  = (const float*)d_in[10];
    const float* bh1  = (const float*)d_in[11];

    _Float16* wp = (_Float16*)d_ws;   // needs 1,376,256 B of workspace

    pack_weights_k<<<WTOT / 256, 256, 0, stream>>>(Wx0, Wh0, Wx1, Wh1, wp);
    film_gru_k<<<64, 512, 0, stream>>>(x, hini, gam, bet,
                                       bx0, bh0, bx1, bh1, wp, (float*)d_out);
}

// Round 2
// 3754.696 us; speedup vs baseline: 1.7784x; 1.7784x over previous
//
#include <hip/hip_runtime.h>

// FiLM-GRU, T=128, B=1024, IN=128, H=256, L=2, fp32 in/out.
// R2: weight-stationary column-split design.
//   Grid = 256 blocks (cooperative) = 16 batch-groups (bg, 64 rows) x 16
//   col-groups (cg, 16 cols). Each block keeps its 84 KB f16 weight slice in
//   LDS for all 128 steps. Hidden states round-trip through global f16
//   buffers in MFMA A-frag layout (coalesced), double-buffered by parity.
//   One 16-block batch-group barrier per step (device-scope atomics);
//   same-bg blocks are blockIdx = bg (mod 16) -> same XCD under %8 placement.

typedef __attribute__((ext_vector_type(8))) _Float16 half8;
typedef __attribute__((ext_vector_type(4))) float   f32x4;

#define T_  128
#define B_  1024
#define IN_ 128
#define H_  256

// ---------------- packed weight layout in d_ws (f16) ----------------
// chunks of 512 = one 16(N)x32(K) B-frag:
// element [lane*8 + j] = W[nt*16 + (lane&15)][kt*32 + (lane>>4)*8 + j]
#define WX0_OFF 0
#define WX0_N   (48 * 4 * 512)
#define WH0_OFF (WX0_OFF + WX0_N)
#define WH0_N   (48 * 8 * 512)
#define WX1_OFF (WH0_OFF + WH0_N)
#define WX1_N   (48 * 8 * 512)
#define WH1_OFF (WX1_OFF + WX1_N)
#define WH1_N   (48 * 8 * 512)
#define WTOT    (WH1_OFF + WH1_N)        // 688128 f16 = 1,376,256 B

// ---------------- d_ws byte offsets ----------------
#define H0B_OFF 1376256                   // 2 parities x 262144 f16 = 1 MB
#define H1B_OFF (H0B_OFF + 1048576)       // 1 MB
#define CTR_OFF (H1B_OFF + 1048576)       // 16 bgs x 32 ints = 2 KB
// total ws use: 3,475,456 B

#define HPAR 262144                       // f16 elems per parity (512 chunks x 512)

__global__ void pack_weights_k(const float* __restrict__ Wx0, const float* __restrict__ Wh0,
                               const float* __restrict__ Wx1, const float* __restrict__ Wh1,
                               _Float16* __restrict__ wp)
{
    int p = blockIdx.x * blockDim.x + threadIdx.x;
    if (p >= WTOT) return;
    const float* src; int q, nk, K;
    if (p < WX1_OFF) {
        if (p < WH0_OFF) { src = Wx0; q = p - WX0_OFF; nk = 4; K = 128; }
        else             { src = Wh0; q = p - WH0_OFF; nk = 8; K = 256; }
    } else {
        if (p < WH1_OFF) { src = Wx1; q = p - WX1_OFF; nk = 8; K = 256; }
        else             { src = Wh1; q = p - WH1_OFF; nk = 8; K = 256; }
    }
    int chunk = q >> 9;
    int e     = q & 511;
    int nt = chunk / nk, kt = chunk - nt * nk;
    int lane = e >> 3, j = e & 7;
    int n = nt * 16 + (lane & 15);
    int k = kt * 32 + ((lane >> 4) << 3) + j;
    wp[p] = (_Float16)src[n * K + k];
}

__device__ __forceinline__ float sigmoid_(float v) { return 1.f / (1.f + __expf(-v)); }
__device__ __forceinline__ float tanh_(float v) {
    float e = __expf(2.f * v);
    return 1.f - 2.f / (e + 1.f);
}

__device__ __forceinline__ half8 cvt_h8f(f32x4 a, f32x4 b) {
    half8 r;
    r[0] = (_Float16)a[0]; r[1] = (_Float16)a[1]; r[2] = (_Float16)a[2]; r[3] = (_Float16)a[3];
    r[4] = (_Float16)b[0]; r[5] = (_Float16)b[1]; r[6] = (_Float16)b[2]; r[7] = (_Float16)b[3];
    return r;
}

#define MFMA(a, b, c) __builtin_amdgcn_mfma_f32_16x16x32_f16((a), (b), (c), 0, 0, 0)

// LDS weight chunk indices (each chunk = 512 f16 = one B-frag):
//  L0X: g*4 + kt            (g=0 z, 1 r, 2 n; kt 0..3)   chunks  0..11
//  L0H: 12 + g*8 + kt                                    chunks 12..35
//  L1X: 36 + g*8 + kt                                    chunks 36..59
//  L1H: 60 + g*8 + kt                                    chunks 60..83

__device__ __forceinline__ void bg_barrier(int* c, int target) {
    __threadfence();
    __syncthreads();
    if (threadIdx.x == 0) {
        __hip_atomic_fetch_add(c, 1, __ATOMIC_ACQ_REL, __HIP_MEMORY_SCOPE_AGENT);
        while (__hip_atomic_load(c, __ATOMIC_ACQUIRE, __HIP_MEMORY_SCOPE_AGENT) < target)
            __builtin_amdgcn_s_sleep(1);
    }
    __syncthreads();
}

__launch_bounds__(256, 1)
__global__ void film_gru_k(const float* __restrict__ x,
                           const float* __restrict__ h_init,
                           const float* __restrict__ gammas,
                           const float* __restrict__ betas,
                           const float* __restrict__ bx0, const float* __restrict__ bh0,
                           const float* __restrict__ bx1, const float* __restrict__ bh1,
                           const _Float16* __restrict__ wp,
                           _Float16* __restrict__ h0b,
                           _Float16* __restrict__ h1b,
                           int* __restrict__ ctr,
                           float* __restrict__ out)
{
    __shared__ __align__(16) _Float16 wlds[84 * 512];     // 86016 B
    __shared__ __align__(16) float bounce[4][16 * 24];    // 6144 B, padded stride 24

    const int tid  = threadIdx.x;
    const int w    = tid >> 6;          // wave 0..3 = row-tile
    const int lane = tid & 63;
    const int l15  = lane & 15;
    const int lq   = lane >> 4;
    const int bg   = blockIdx.x & 15;   // batch group (rows bg*64..+64); same-bg => same XCD (%8)
    const int cg   = blockIdx.x >> 4;   // col group (cols cg*16..+16)
    const int b0   = bg * 64;
    const int rowbase = b0 + w * 16;
    const int col  = cg * 16 + l15;

    int* bctr = ctr + bg * 32;

    // ---- stage weight slice into LDS (once) ----
    for (int i = tid; i < 84 * 64; i += 256) {
        int c = i >> 6, e = i & 63;
        size_t src;
        if (c < 12)      { int g = c >> 2;   int kt = c & 3;  src = WX0_OFF + (size_t)(((g*16 + cg)*4) + kt) * 512; }
        else if (c < 36) { int q = c - 12;   int g = q >> 3;  int kt = q & 7; src = WH0_OFF + (size_t)(((g*16 + cg)*8) + kt) * 512; }
        else if (c < 60) { int q = c - 36;   int g = q >> 3;  int kt = q & 7; src = WX1_OFF + (size_t)(((g*16 + cg)*8) + kt) * 512; }
        else             { int q = c - 60;   int g = q >> 3;  int kt = q & 7; src = WH1_OFF + (size_t)(((g*16 + cg)*8) + kt) * 512; }
        *(half8*)&wlds[(size_t)c * 512 + (size_t)e * 8] = *(const half8*)(wp + src + (size_t)e * 8);
    }

    // ---- hoist per-lane constants ----
    float bz0 = bx0[col] + bh0[col];
    float br0 = bx0[256 + col] + bh0[256 + col];
    float bxn0 = bx0[512 + col], bhn0 = bh0[512 + col];
    float bz1 = bx1[col] + bh1[col];
    float br1 = bx1[256 + col] + bh1[256 + col];
    float bxn1 = bx1[512 + col], bhn1 = bh1[512 + col];

    float g0v[4], be0v[4], g1v[4], be1v[4], hr0[4], hr1[4];
    #pragma unroll
    for (int g = 0; g < 4; g++) {
        size_t row = rowbase + lq * 4 + g;
        size_t gi = row * H_ + col;
        g0v[g] = gammas[gi];              be0v[g] = betas[gi];
        g1v[g] = gammas[(size_t)B_ * H_ + gi]; be1v[g] = betas[(size_t)B_ * H_ + gi];
        hr0[g] = h_init[gi];
        hr1[g] = h_init[(size_t)B_ * H_ + gi];
    }

    // ---- fill parity-0 h buffers (A-frag chunk layout) ----
    // chunk(bg,rt,kt) = (bg*4+rt)*8 + kt ; this block owns kt=cg>>1, lane-half cg&1
    const int mykt   = cg >> 1;
    const int lhalf  = (cg & 1) * 32;
    const size_t mychunk = ((size_t)(bg * 4 + w) * 8 + mykt) * 512;
    if (lane < 32) {
        int row = lane & 15, ch = lane >> 4;
        const float* s0 = h_init + (size_t)(rowbase + row) * H_ + cg * 16 + ch * 8;
        half8 v0 = cvt_h8f(*(const f32x4*)s0, *(const f32x4*)(s0 + 4));
        const float* s1 = s0 + (size_t)B_ * H_;
        half8 v1 = cvt_h8f(*(const f32x4*)s1, *(const f32x4*)(s1 + 4));
        size_t d = mychunk + (size_t)(lhalf + lane) * 8;
        *(half8*)&h0b[d] = v0;
        *(half8*)&h1b[d] = v1;
    }

    int epoch = 0;
    bg_barrier(bctr, 16 * (++epoch));     // parity-0 fills visible

    const f32x4 zero4 = {0.f, 0.f, 0.f, 0.f};
    const size_t hchunkbase = (size_t)(bg * 4 + w) * 8 * 512;

    for (int t = 0; t < T_; t++) {
        const int rp = t & 1, wpar = rp ^ 1;

        // ================= phase 0 : layer 0 =================
        f32x4 az = zero4, ar = zero4, axn = zero4, ahn = zero4;

        // issue global loads first
        const float* xb = x + (size_t)t * B_ * IN_ + (size_t)(rowbase + l15) * IN_ + lq * 8;
        f32x4 xr[8];
        #pragma unroll
        for (int kt = 0; kt < 4; kt++) {
            xr[2*kt]   = *(const f32x4*)(xb + kt * 32);
            xr[2*kt+1] = *(const f32x4*)(xb + kt * 32 + 4);
        }
        const _Float16* h0r = h0b + (size_t)rp * HPAR + hchunkbase + (size_t)lane * 8;
        half8 ha[8];
        #pragma unroll
        for (int kt = 0; kt < 8; kt++) ha[kt] = *(const half8*)(h0r + (size_t)kt * 512);

        #pragma unroll
        for (int kt = 0; kt < 4; kt++) {
            half8 a = cvt_h8f(xr[2*kt], xr[2*kt+1]);
            az  = MFMA(a, *(const half8*)&wlds[(0*4 + kt) * 512 + lane * 8], az);
            ar  = MFMA(a, *(const half8*)&wlds[(1*4 + kt) * 512 + lane * 8], ar);
            axn = MFMA(a, *(const half8*)&wlds[(2*4 + kt) * 512 + lane * 8], axn);
        }
        #pragma unroll
        for (int kt = 0; kt < 8; kt++) {
            az  = MFMA(ha[kt], *(const half8*)&wlds[(12 + 0*8 + kt) * 512 + lane * 8], az);
            ar  = MFMA(ha[kt], *(const half8*)&wlds[(12 + 1*8 + kt) * 512 + lane * 8], ar);
            ahn = MFMA(ha[kt], *(const half8*)&wlds[(12 + 2*8 + kt) * 512 + lane * 8], ahn);
        }

        #pragma unroll
        for (int g = 0; g < 4; g++) {
            float z = sigmoid_(az[g] + bz0);
            float r = sigmoid_(ar[g] + br0);
            float n = tanh_(axn[g] + bxn0 + r * (ahn[g] + bhn0));
            float h = (1.f - z) * n + z * hr0[g];
            h = g0v[g] * h + be0v[g];
            hr0[g] = h;
            bounce[w][(lq * 4 + g) * 24 + l15] = h;
        }
        __syncthreads();
        if (lane < 32) {
            int row = lane & 15, ch = lane >> 4;
            const float* bp = &bounce[w][row * 24 + ch * 8];
            half8 v = cvt_h8f(*(const f32x4*)bp, *(const f32x4*)(bp + 4));
            *(half8*)&h0b[(size_t)wpar * HPAR + mychunk + (size_t)(lhalf + lane) * 8] = v;
        }

        bg_barrier(bctr, 16 * (++epoch));   // out0 slices visible

        // ================= phase 1 : layer 1 =================
        az = zero4; ar = zero4; axn = zero4; ahn = zero4;

        const _Float16* o0r = h0b + (size_t)wpar * HPAR + hchunkbase + (size_t)lane * 8;
        const _Float16* h1r = h1b + (size_t)rp   * HPAR + hchunkbase + (size_t)lane * 8;
        half8 a0[8], a1[8];
        #pragma unroll
        for (int kt = 0; kt < 8; kt++) a0[kt] = *(const half8*)(o0r + (size_t)kt * 512);
        #pragma unroll
        for (int kt = 0; kt < 8; kt++) a1[kt] = *(const half8*)(h1r + (size_t)kt * 512);

        #pragma unroll
        for (int kt = 0; kt < 8; kt++) {
            az  = MFMA(a0[kt], *(const half8*)&wlds[(36 + 0*8 + kt) * 512 + lane * 8], az);
            ar  = MFMA(a0[kt], *(const half8*)&wlds[(36 + 1*8 + kt) * 512 + lane * 8], ar);
            axn = MFMA(a0[kt], *(const half8*)&wlds[(36 + 2*8 + kt) * 512 + lane * 8], axn);
        }
        #pragma unroll
        for (int kt = 0; kt < 8; kt++) {
            az  = MFMA(a1[kt], *(const half8*)&wlds[(60 + 0*8 + kt) * 512 + lane * 8], az);
            ar  = MFMA(a1[kt], *(const half8*)&wlds[(60 + 1*8 + kt) * 512 + lane * 8], ar);
            ahn = MFMA(a1[kt], *(const half8*)&wlds[(60 + 2*8 + kt) * 512 + lane * 8], ahn);
        }

        #pragma unroll
        for (int g = 0; g < 4; g++) {
            float z = sigmoid_(az[g] + bz1);
            float r = sigmoid_(ar[g] + br1);
            float n = tanh_(axn[g] + bxn1 + r * (ahn[g] + bhn1));
            float h = (1.f - z) * n + z * hr1[g];
            h = g1v[g] * h + be1v[g];
            hr1[g] = h;
            bounce[w][(lq * 4 + g) * 24 + l15] = h;
        }
        __syncthreads();
        {   // coalesced fp32 output store (all 64 lanes)
            int row = lane >> 2, coff = (lane & 3) * 4;
            f32x4 v = *(const f32x4*)&bounce[w][row * 24 + coff];
            *(f32x4*)&out[(size_t)t * B_ * H_ + (size_t)(rowbase + row) * H_ + cg * 16 + coff] = v;
        }
        if (lane < 32) {
            int row = lane & 15, ch = lane >> 4;
            const float* bp = &bounce[w][row * 24 + ch * 8];
            half8 v = cvt_h8f(*(const f32x4*)bp, *(const f32x4*)(bp + 4));
            *(half8*)&h1b[(size_t)wpar * HPAR + mychunk + (size_t)(lhalf + lane) * 8] = v;
        }
        // no trailing barrier needed: next step's mid barrier orders phase1
        // writes/reads via double-buffered parity (see analysis)
    }

    // ---- final states ----
    size_t base = (size_t)T_ * B_ * H_;
    #pragma unroll
    for (int g = 0; g < 4; g++) {
        size_t row = rowbase + lq * 4 + g;
        out[base + row * H_ + col] = hr0[g];
        out[base + (size_t)B_ * H_ + row * H_ + col] = hr1[g];
    }
}

extern "C" void kernel_launch(void* const* d_in, const int* in_sizes, int n_in,
                              void* d_out, int out_size, void* d_ws, size_t ws_size,
                              hipStream_t stream)
{
    const float* x    = (const float*)d_in[0];
    const float* hini = (const float*)d_in[1];
    const float* gam  = (const float*)d_in[2];
    const float* bet  = (const float*)d_in[3];
    const float* Wx0  = (const float*)d_in[4];
    const float* bx0  = (const float*)d_in[5];
    const float* Wh0  = (const float*)d_in[6];
    const float* bh0  = (const float*)d_in[7];
    const float* Wx1  = (const float*)d_in[8];
    const float* bx1  = (const float*)d_in[9];
    const float* Wh1  = (const float*)d_in[10];
    const float* bh1  = (const float*)d_in[11];

    _Float16* wp  = (_Float16*)d_ws;
    _Float16* h0b = (_Float16*)((char*)d_ws + H0B_OFF);
    _Float16* h1b = (_Float16*)((char*)d_ws + H1B_OFF);
    int*      ctr = (int*)((char*)d_ws + CTR_OFF);
    float*    outp = (float*)d_out;

    hipMemsetAsync(ctr, 0, 16 * 32 * sizeof(int), stream);
    pack_weights_k<<<WTOT / 256, 256, 0, stream>>>(Wx0, Wh0, Wx1, Wh1, wp);

    void* args[] = { (void*)&x, (void*)&hini, (void*)&gam, (void*)&bet,
                     (void*)&bx0, (void*)&bh0, (void*)&bx1, (void*)&bh1,
                     (void*)&wp, (void*)&h0b, (void*)&h1b, (void*)&ctr, (void*)&outp };
    hipLaunchCooperativeKernel((void*)film_gru_k, dim3(256), dim3(256),
                               args, 0, stream);
}

// Round 3
// 1514.313 us; speedup vs baseline: 4.4094x; 2.4795x over previous
//
#include <hip/hip_runtime.h>

// FiLM-GRU, T=128, B=1024, IN=128, H=256, L=2, fp32 in/out.
// R3: weight-stationary column-split (as R2) with fixed barrier:
//   - RELAXED polling (no buffer_inv per poll), single RELEASE add +
//     single ACQUIRE load per block per step, thread 0 only.
//   - no __threadfence (syncthreads drains vmcnt; release add emits wbl2).
//   - phase-1 a0 fragments reused as next step's phase-0 h fragments
//     (identical addresses) -> phase 0 has zero exposed global latency.
//   - x for t+1 prefetched before the barrier.

typedef __attribute__((ext_vector_type(8))) _Float16 half8;
typedef __attribute__((ext_vector_type(4))) float   f32x4;

#define T_  128
#define B_  1024
#define IN_ 128
#define H_  256

// ---------------- packed weight layout in d_ws (f16) ----------------
// chunks of 512 = one 16(N)x32(K) B-frag:
// element [lane*8 + j] = W[nt*16 + (lane&15)][kt*32 + (lane>>4)*8 + j]
#define WX0_OFF 0
#define WX0_N   (48 * 4 * 512)
#define WH0_OFF (WX0_OFF + WX0_N)
#define WH0_N   (48 * 8 * 512)
#define WX1_OFF (WH0_OFF + WH0_N)
#define WX1_N   (48 * 8 * 512)
#define WH1_OFF (WX1_OFF + WX1_N)
#define WH1_N   (48 * 8 * 512)
#define WTOT    (WH1_OFF + WH1_N)        // 688128 f16 = 1,376,256 B

// ---------------- d_ws byte offsets ----------------
#define H0B_OFF 1376256                   // 2 parities x 262144 f16 = 1 MB
#define H1B_OFF (H0B_OFF + 1048576)       // 1 MB
#define CTR_OFF (H1B_OFF + 1048576)       // 16 bgs x 32 ints = 2 KB

#define HPAR 262144                       // f16 elems per parity

__global__ void pack_weights_k(const float* __restrict__ Wx0, const float* __restrict__ Wh0,
                               const float* __restrict__ Wx1, const float* __restrict__ Wh1,
                               _Float16* __restrict__ wp)
{
    int p = blockIdx.x * blockDim.x + threadIdx.x;
    if (p >= WTOT) return;
    const float* src; int q, nk, K;
    if (p < WX1_OFF) {
        if (p < WH0_OFF) { src = Wx0; q = p - WX0_OFF; nk = 4; K = 128; }
        else             { src = Wh0; q = p - WH0_OFF; nk = 8; K = 256; }
    } else {
        if (p < WH1_OFF) { src = Wx1; q = p - WX1_OFF; nk = 8; K = 256; }
        else             { src = Wh1; q = p - WH1_OFF; nk = 8; K = 256; }
    }
    int chunk = q >> 9;
    int e     = q & 511;
    int nt = chunk / nk, kt = chunk - nt * nk;
    int lane = e >> 3, j = e & 7;
    int n = nt * 16 + (lane & 15);
    int k = kt * 32 + ((lane >> 4) << 3) + j;
    wp[p] = (_Float16)src[n * K + k];
}

__device__ __forceinline__ float sigmoid_(float v) { return 1.f / (1.f + __expf(-v)); }
__device__ __forceinline__ float tanh_(float v) {
    float e = __expf(2.f * v);
    return 1.f - 2.f / (e + 1.f);
}

__device__ __forceinline__ half8 cvt_h8f(f32x4 a, f32x4 b) {
    half8 r;
    r[0] = (_Float16)a[0]; r[1] = (_Float16)a[1]; r[2] = (_Float16)a[2]; r[3] = (_Float16)a[3];
    r[4] = (_Float16)b[0]; r[5] = (_Float16)b[1]; r[6] = (_Float16)b[2]; r[7] = (_Float16)b[3];
    return r;
}

#define MFMA(a, b, c) __builtin_amdgcn_mfma_f32_16x16x32_f16((a), (b), (c), 0, 0, 0)

// LDS weight chunk indices (chunk = 512 f16 = one B-frag):
//  L0X: g*4 + kt (kt 0..3) chunks 0..11 | L0H: 12+g*8+kt | L1X: 36+g*8+kt | L1H: 60+g*8+kt

// Barrier: one RELEASE add (wbl2) + relaxed poll + one ACQUIRE load (inv)
// per block per step. __syncthreads() before provides vmcnt(0) drain of all
// waves' stores into L2; release add makes them device-visible.
__device__ __forceinline__ void bg_barrier(int* c, int target) {
    __syncthreads();
    if (threadIdx.x == 0) {
        __hip_atomic_fetch_add(c, 1, __ATOMIC_RELEASE, __HIP_MEMORY_SCOPE_AGENT);
        while (__hip_atomic_load(c, __ATOMIC_RELAXED, __HIP_MEMORY_SCOPE_AGENT) < target)
            __builtin_amdgcn_s_sleep(1);
        (void)__hip_atomic_load(c, __ATOMIC_ACQUIRE, __HIP_MEMORY_SCOPE_AGENT);
    }
    __syncthreads();
}

__launch_bounds__(256, 1)
__global__ void film_gru_k(const float* __restrict__ x,
                           const float* __restrict__ h_init,
                           const float* __restrict__ gammas,
                           const float* __restrict__ betas,
                           const float* __restrict__ bx0, const float* __restrict__ bh0,
                           const float* __restrict__ bx1, const float* __restrict__ bh1,
                           const _Float16* __restrict__ wp,
                           _Float16* __restrict__ h0b,
                           _Float16* __restrict__ h1b,
                           int* __restrict__ ctr,
                           float* __restrict__ out)
{
    __shared__ __align__(16) _Float16 wlds[84 * 512];     // 86016 B
    __shared__ __align__(16) float bounce[4][16 * 24];    // 6144 B

    const int tid  = threadIdx.x;
    const int w    = tid >> 6;          // wave 0..3 = row-tile
    const int lane = tid & 63;
    const int l15  = lane & 15;
    const int lq   = lane >> 4;
    const int bg   = blockIdx.x & 15;   // same-bg blocks -> same XCD under %8 placement
    const int cg   = blockIdx.x >> 4;
    const int b0   = bg * 64;
    const int rowbase = b0 + w * 16;
    const int col  = cg * 16 + l15;

    int* bctr = ctr + bg * 32;

    // ---- stage weight slice into LDS (once) ----
    for (int i = tid; i < 84 * 64; i += 256) {
        int c = i >> 6, e = i & 63;
        size_t src;
        if (c < 12)      { int g = c >> 2;   int kt = c & 3;  src = WX0_OFF + (size_t)(((g*16 + cg)*4) + kt) * 512; }
        else if (c < 36) { int q = c - 12;   int g = q >> 3;  int kt = q & 7; src = WH0_OFF + (size_t)(((g*16 + cg)*8) + kt) * 512; }
        else if (c < 60) { int q = c - 36;   int g = q >> 3;  int kt = q & 7; src = WX1_OFF + (size_t)(((g*16 + cg)*8) + kt) * 512; }
        else             { int q = c - 60;   int g = q >> 3;  int kt = q & 7; src = WH1_OFF + (size_t)(((g*16 + cg)*8) + kt) * 512; }
        *(half8*)&wlds[(size_t)c * 512 + (size_t)e * 8] = *(const half8*)(wp + src + (size_t)e * 8);
    }

    // ---- hoist per-lane constants ----
    float bz0 = bx0[col] + bh0[col];
    float br0 = bx0[256 + col] + bh0[256 + col];
    float bxn0 = bx0[512 + col], bhn0 = bh0[512 + col];
    float bz1 = bx1[col] + bh1[col];
    float br1 = bx1[256 + col] + bh1[256 + col];
    float bxn1 = bx1[512 + col], bhn1 = bh1[512 + col];

    float g0v[4], be0v[4], g1v[4], be1v[4], hr0[4], hr1[4];
    #pragma unroll
    for (int g = 0; g < 4; g++) {
        size_t row = rowbase + lq * 4 + g;
        size_t gi = row * H_ + col;
        g0v[g] = gammas[gi];              be0v[g] = betas[gi];
        g1v[g] = gammas[(size_t)B_ * H_ + gi]; be1v[g] = betas[(size_t)B_ * H_ + gi];
        hr0[g] = h_init[gi];
        hr1[g] = h_init[(size_t)B_ * H_ + gi];
    }

    // ---- fill parity-0 h buffers (A-frag chunk layout) ----
    const int mykt   = cg >> 1;
    const int lhalf  = (cg & 1) * 32;
    const size_t mychunk = ((size_t)(bg * 4 + w) * 8 + mykt) * 512;
    if (lane < 32) {
        int row = lane & 15, ch = lane >> 4;
        const float* s0 = h_init + (size_t)(rowbase + row) * H_ + cg * 16 + ch * 8;
        half8 v0 = cvt_h8f(*(const f32x4*)s0, *(const f32x4*)(s0 + 4));
        const float* s1 = s0 + (size_t)B_ * H_;
        half8 v1 = cvt_h8f(*(const f32x4*)s1, *(const f32x4*)(s1 + 4));
        size_t d = mychunk + (size_t)(lhalf + lane) * 8;
        *(half8*)&h0b[d] = v0;
        *(half8*)&h1b[d] = v1;
    }

    int epoch = 0;
    bg_barrier(bctr, 16 * (++epoch));     // parity-0 fills visible

    const f32x4 zero4 = {0.f, 0.f, 0.f, 0.f};
    const size_t hchunkbase = (size_t)(bg * 4 + w) * 8 * 512;

    // prefetch: h0 A-frags for t=0 (parity 0) and x for t=0
    half8 a0c[8];
    {
        const _Float16* h0r = h0b + hchunkbase + (size_t)lane * 8;
        #pragma unroll
        for (int kt = 0; kt < 8; kt++) a0c[kt] = *(const half8*)(h0r + (size_t)kt * 512);
    }
    f32x4 xr[8];
    {
        const float* xb = x + (size_t)(rowbase + l15) * IN_ + lq * 8;
        #pragma unroll
        for (int kt = 0; kt < 4; kt++) {
            xr[2*kt]   = *(const f32x4*)(xb + kt * 32);
            xr[2*kt+1] = *(const f32x4*)(xb + kt * 32 + 4);
        }
    }

    for (int t = 0; t < T_; t++) {
        const int rp = t & 1, wpar = rp ^ 1;

        // ================= phase 0 : layer 0 =================
        // inputs: xr (regs), a0c (regs, = h0(t) A-frags), wlds
        f32x4 az = zero4, ar = zero4, axn = zero4, ahn = zero4;

        #pragma unroll
        for (int kt = 0; kt < 4; kt++) {
            half8 a = cvt_h8f(xr[2*kt], xr[2*kt+1]);
            az  = MFMA(a, *(const half8*)&wlds[(0*4 + kt) * 512 + lane * 8], az);
            ar  = MFMA(a, *(const half8*)&wlds[(1*4 + kt) * 512 + lane * 8], ar);
            axn = MFMA(a, *(const half8*)&wlds[(2*4 + kt) * 512 + lane * 8], axn);
        }
        #pragma unroll
        for (int kt = 0; kt < 8; kt++) {
            az  = MFMA(a0c[kt], *(const half8*)&wlds[(12 + 0*8 + kt) * 512 + lane * 8], az);
            ar  = MFMA(a0c[kt], *(const half8*)&wlds[(12 + 1*8 + kt) * 512 + lane * 8], ar);
            ahn = MFMA(a0c[kt], *(const half8*)&wlds[(12 + 2*8 + kt) * 512 + lane * 8], ahn);
        }

        // prefetch x for t+1 (overlaps elementwise + barrier wait)
        {
            int tn = (t + 1 < T_) ? t + 1 : t;
            const float* xb = x + (size_t)tn * B_ * IN_ + (size_t)(rowbase + l15) * IN_ + lq * 8;
            #pragma unroll
            for (int kt = 0; kt < 4; kt++) {
                xr[2*kt]   = *(const f32x4*)(xb + kt * 32);
                xr[2*kt+1] = *(const f32x4*)(xb + kt * 32 + 4);
            }
        }

        #pragma unroll
        for (int g = 0; g < 4; g++) {
            float z = sigmoid_(az[g] + bz0);
            float r = sigmoid_(ar[g] + br0);
            float n = tanh_(axn[g] + bxn0 + r * (ahn[g] + bhn0));
            float h = (1.f - z) * n + z * hr0[g];
            h = g0v[g] * h + be0v[g];
            hr0[g] = h;
            bounce[w][(lq * 4 + g) * 24 + l15] = h;
        }
        __syncthreads();
        if (lane < 32) {
            int row = lane & 15, ch = lane >> 4;
            const float* bp = &bounce[w][row * 24 + ch * 8];
            half8 v = cvt_h8f(*(const f32x4*)bp, *(const f32x4*)(bp + 4));
            *(half8*)&h0b[(size_t)wpar * HPAR + mychunk + (size_t)(lhalf + lane) * 8] = v;
        }

        bg_barrier(bctr, 16 * (++epoch));   // out0 slices visible

        // ================= phase 1 : layer 1 =================
        // a0 = out0 A-frags (also next step's h0 A-frags -> kept in a0c)
        const _Float16* o0r = h0b + (size_t)wpar * HPAR + hchunkbase + (size_t)lane * 8;
        const _Float16* h1r = h1b + (size_t)rp   * HPAR + hchunkbase + (size_t)lane * 8;
        half8 a1[8];
        #pragma unroll
        for (int kt = 0; kt < 8; kt++) a0c[kt] = *(const half8*)(o0r + (size_t)kt * 512);
        #pragma unroll
        for (int kt = 0; kt < 8; kt++) a1[kt] = *(const half8*)(h1r + (size_t)kt * 512);

        az = zero4; ar = zero4; axn = zero4; ahn = zero4;
        #pragma unroll
        for (int kt = 0; kt < 8; kt++) {
            az  = MFMA(a0c[kt], *(const half8*)&wlds[(36 + 0*8 + kt) * 512 + lane * 8], az);
            ar  = MFMA(a0c[kt], *(const half8*)&wlds[(36 + 1*8 + kt) * 512 + lane * 8], ar);
            axn = MFMA(a0c[kt], *(const half8*)&wlds[(36 + 2*8 + kt) * 512 + lane * 8], axn);
        }
        #pragma unroll
        for (int kt = 0; kt < 8; kt++) {
            az  = MFMA(a1[kt], *(const half8*)&wlds[(60 + 0*8 + kt) * 512 + lane * 8], az);
            ar  = MFMA(a1[kt], *(const half8*)&wlds[(60 + 1*8 + kt) * 512 + lane * 8], ar);
            ahn = MFMA(a1[kt], *(const half8*)&wlds[(60 + 2*8 + kt) * 512 + lane * 8], ahn);
        }

        #pragma unroll
        for (int g = 0; g < 4; g++) {
            float z = sigmoid_(az[g] + bz1);
            float r = sigmoid_(ar[g] + br1);
            float n = tanh_(axn[g] + bxn1 + r * (ahn[g] + bhn1));
            float h = (1.f - z) * n + z * hr1[g];
            h = g1v[g] * h + be1v[g];
            hr1[g] = h;
            bounce[w][(lq * 4 + g) * 24 + l15] = h;
        }
        __syncthreads();
        {   // coalesced fp32 output store
            int row = lane >> 2, coff = (lane & 3) * 4;
            f32x4 v = *(const f32x4*)&bounce[w][row * 24 + coff];
            *(f32x4*)&out[(size_t)t * B_ * H_ + (size_t)(rowbase + row) * H_ + cg * 16 + coff] = v;
        }
        if (lane < 32) {
            int row = lane & 15, ch = lane >> 4;
            const float* bp = &bounce[w][row * 24 + ch * 8];
            half8 v = cvt_h8f(*(const f32x4*)bp, *(const f32x4*)(bp + 4));
            *(half8*)&h1b[(size_t)wpar * HPAR + mychunk + (size_t)(lhalf + lane) * 8] = v;
        }
        // next step's mid barrier orders phase-1 writes (double-buffered parity)
    }

    // ---- final states ----
    size_t base = (size_t)T_ * B_ * H_;
    #pragma unroll
    for (int g = 0; g < 4; g++) {
        size_t row = rowbase + lq * 4 + g;
        out[base + row * H_ + col] = hr0[g];
        out[base + (size_t)B_ * H_ + row * H_ + col] = hr1[g];
    }
}

extern "C" void kernel_launch(void* const* d_in, const int* in_sizes, int n_in,
                              void* d_out, int out_size, void* d_ws, size_t ws_size,
                              hipStream_t stream)
{
    const float* x    = (const float*)d_in[0];
    const float* hini = (const float*)d_in[1];
    const float* gam  = (const float*)d_in[2];
    const float* bet  = (const float*)d_in[3];
    const float* Wx0  = (const float*)d_in[4];
    const float* bx0  = (const float*)d_in[5];
    const float* Wh0  = (const float*)d_in[6];
    const float* bh0  = (const float*)d_in[7];
    const float* Wx1  = (const float*)d_in[8];
    const float* bx1  = (const float*)d_in[9];
    const float* Wh1  = (const float*)d_in[10];
    const float* bh1  = (const float*)d_in[11];

    _Float16* wp  = (_Float16*)d_ws;
    _Float16* h0b = (_Float16*)((char*)d_ws + H0B_OFF);
    _Float16* h1b = (_Float16*)((char*)d_ws + H1B_OFF);
    int*      ctr = (int*)((char*)d_ws + CTR_OFF);
    float*    outp = (float*)d_out;

    hipMemsetAsync(ctr, 0, 16 * 32 * sizeof(int), stream);
    pack_weights_k<<<WTOT / 256, 256, 0, stream>>>(Wx0, Wh0, Wx1, Wh1, wp);

    void* args[] = { (void*)&x, (void*)&hini, (void*)&gam, (void*)&bet,
                     (void*)&bx0, (void*)&bh0, (void*)&bx1, (void*)&bh1,
                     (void*)&wp, (void*)&h0b, (void*)&h1b, (void*)&ctr, (void*)&outp };
    hipLaunchCooperativeKernel((void*)film_gru_k, dim3(256), dim3(256),
                               args, 0, stream);
}